// Round 1
// baseline (174.046 us; speedup 1.0000x reference)
//
#include <hip/hip_runtime.h>

#define BATCH 16
#define CH    16
#define HH    128
#define WW    128
#define NC    8           // n_convs
#define TS    32          // spatial tile
#define HALO  (TS + 2)    // 34

// Fused KAN conv:
//   features per element: f0=silu(v), f1=tanh(v), f2=2t^2 (=T2+1), f3=4t^3-3t (=T3)
//   bias_j = sum_i (W0 - W2)[j,i]  absorbs T0 and the "+1" shift of f2, and makes
//   all features exactly 0 at the zero padding (matches reference pad semantics).
__global__ __launch_bounds__(256, 4)
void kan_conv_kernel(const float* __restrict__ x,
                     const float* __restrict__ cheby,   // (8,9,4)
                     const float* __restrict__ bwt,     // (8,9)
                     const float* __restrict__ scl,     // (8,9)
                     float* __restrict__ out)           // (16, 128, 128, 128)
{
    __shared__ float4 feat[HALO][HALO];   // 18.5 KB
    __shared__ float4 wgt[9 * NC];        // [tap*8 + j] = (bw, W1, W2, W3)
    __shared__ float  bias[NC];

    const int tx  = threadIdx.x;          // 0..31
    const int ty  = threadIdx.y;          // 0..7
    const int tid = ty * 32 + tx;

    const int w0 = blockIdx.x * TS;
    const int h0 = blockIdx.y * TS;
    const int bz = blockIdx.z;            // plane = b*CH + c

    // ---- stage combined weights into LDS ----
    if (tid < 9 * NC) {
        int j = tid / 9, i = tid % 9;
        float s  = scl[j * 9 + i];
        float w1 = cheby[(j * 9 + i) * 4 + 1] * s;
        float w2 = cheby[(j * 9 + i) * 4 + 2] * s;
        float w3 = cheby[(j * 9 + i) * 4 + 3] * s;
        wgt[i * NC + j] = make_float4(bwt[j * 9 + i], w1, w2, w3);
    } else if (tid >= 128 && tid < 128 + NC) {
        int j = tid - 128;
        float b = 0.f;
        #pragma unroll
        for (int i = 0; i < 9; ++i)
            b += (cheby[(j * 9 + i) * 4 + 0] - cheby[(j * 9 + i) * 4 + 2]) * scl[j * 9 + i];
        bias[j] = b;
    }

    // ---- load halo tile, compute features into LDS ----
    const float* xp = x + (size_t)bz * HH * WW;
    for (int idx = tid; idx < HALO * HALO; idx += 256) {
        int r  = idx / HALO;
        int c  = idx - r * HALO;
        int gh = h0 + r - 1;
        int gw = w0 + c - 1;
        float v = 0.f;
        if ((unsigned)gh < (unsigned)HH && (unsigned)gw < (unsigned)WW)
            v = xp[gh * WW + gw];
        float e2 = __expf(2.f * v);
        float t  = 1.f - 2.f * __builtin_amdgcn_rcpf(e2 + 1.f);   // tanh(v)
        float sg = __builtin_amdgcn_rcpf(1.f + __expf(-v));       // sigmoid(v)
        float f0 = v * sg;                                        // silu
        float f2 = 2.f * t * t;                                   // T2 + 1
        float f3 = 2.f * t * (f2 - 1.f) - t;                      // T3 = 2t*T2 - t
        feat[r][c] = make_float4(f0, t, f2, f3);
    }
    __syncthreads();

    // ---- conv: each thread does 4 consecutive rows x 1 col, 8 outputs each ----
    float acc[4][NC];
    #pragma unroll
    for (int p = 0; p < 4; ++p)
        #pragma unroll
        for (int j = 0; j < NC; ++j)
            acc[p][j] = bias[j];

    #pragma unroll 1   // keep per-tap weights (32 VGPRs) from being hoisted x9
    for (int i = 0; i < 9; ++i) {
        const int dr = i / 3, dc = i - 3 * (i / 3);
        float4 w[NC];
        #pragma unroll
        for (int j = 0; j < NC; ++j) w[j] = wgt[i * NC + j];
        #pragma unroll
        for (int p = 0; p < 4; ++p) {
            float4 f = feat[ty * 4 + p + dr][tx + dc];
            #pragma unroll
            for (int j = 0; j < NC; ++j) {
                acc[p][j] += w[j].x * f.x;
                acc[p][j] += w[j].y * f.y;
                acc[p][j] += w[j].z * f.z;
                acc[p][j] += w[j].w * f.w;
            }
        }
    }

    // ---- store: out[b, c*8+j, h, w] ----
    #pragma unroll
    for (int p = 0; p < 4; ++p) {
        const int gh = h0 + ty * 4 + p;
        float* op = out + ((size_t)(bz * NC) * HH + gh) * WW + w0 + tx;
        #pragma unroll
        for (int j = 0; j < NC; ++j)
            op[(size_t)j * HH * WW] = acc[p][j];
    }
}

extern "C" void kernel_launch(void* const* d_in, const int* in_sizes, int n_in,
                              void* d_out, int out_size, void* d_ws, size_t ws_size,
                              hipStream_t stream) {
    const float* x     = (const float*)d_in[0];
    const float* cheby = (const float*)d_in[1];
    const float* bwt   = (const float*)d_in[2];
    const float* scl   = (const float*)d_in[3];
    float* out = (float*)d_out;

    dim3 grid(WW / TS, HH / TS, BATCH * CH);   // 4 x 4 x 256
    dim3 block(32, 8);
    hipLaunchKernelGGL(kan_conv_kernel, grid, block, 0, stream, x, cheby, bwt, scl, out);
}